// Round 20
// baseline (324.911 us; speedup 1.0000x reference)
//
#include <hip/hip_runtime.h>
#include <hip/hip_fp16.h>
#include <stdint.h>

#define T_STEPS 8
#define FIN 3
#define HID 32
#define NEG_SLOPE 0.2f
#define LOG2E 1.4426950408889634f

typedef __fp16 v4h __attribute__((ext_vector_type(4)));
typedef __fp16 v2h __attribute__((ext_vector_type(2)));
typedef float  v4f __attribute__((ext_vector_type(4)));

__device__ __forceinline__ float lrelu(float x) { return x > 0.f ? x : NEG_SLOPE * x; }
__device__ __forceinline__ float sigmoidf(float x) { return 1.f / (1.f + __expf(-x)); }

__device__ __forceinline__ float fdot2h(__half2 a, __half2 b, float c) {
#if __has_builtin(__builtin_amdgcn_fdot2)
    union { __half2 h; v2h v; } ua, ub;
    ua.h = a; ub.h = b;
    return __builtin_amdgcn_fdot2(ua.v, ub.v, c, false);
#else
    float2 fa = __half22float2(a), fb = __half22float2(b);
    return c + fa.x * fb.x + fa.y * fb.y;
#endif
}

// ---------------- edge dtype detection (int64 vs int32) ----------------
__global__ void detect_kernel(const int* ei32, int nElems, int* flag) {
    __shared__ int any_nonzero;
    if (threadIdx.x == 0) any_nonzero = 0;
    __syncthreads();
    int idx = 1 + 2 * (int)threadIdx.x;  // odd int32 slots
    if (idx < nElems && ei32[idx] != 0) any_nonzero = 1;  // benign race
    __syncthreads();
    if (threadIdx.x == 0) *flag = (any_nonzero ? 0 : 1);  // 1 => int64
}

__device__ __forceinline__ int get_edge(const void* ei, int is64, long long idx) {
    if (is64) return (int)((const long long*)ei)[idx];
    return ((const int*)ei)[idx];
}

__global__ void init_kernel(int* cnt, int N) {
    int i = blockIdx.x * 256 + threadIdx.x;
    if (i < N) cnt[i] = 1;  // self-loop pre-counted
}

// fused: int32 conversion + validity clamp + per-dst count
__global__ void conv_count_kernel(const void* ei, const int* flag, int E, int N,
                                  int* src32, int* dst32, int* cnt) {
    int e = blockIdx.x * 256 + threadIdx.x;
    if (e >= E) return;
    int is64 = *flag;
    int s = get_edge(ei, is64, e);
    int d = get_edge(ei, is64, (long long)E + e);
    if ((unsigned)s >= (unsigned)N) s = 0;  // safety clamp
    src32[e] = s;
    int dd = ((unsigned)d < (unsigned)N) ? d : 0x7fffffff;  // sentinel: excluded everywhere
    dst32[e] = dd;
    if (dd < N) atomicAdd(&cnt[dd], 1);
}

// hierarchical scan
__global__ __launch_bounds__(256) void scan1_kernel(const int* cnt, int* rowptr, int* bsum, int n) {
    __shared__ int sm[256];
    int i = blockIdx.x * 256 + threadIdx.x;
    int v = (i < n) ? cnt[i] : 0;
    sm[threadIdx.x] = v;
    __syncthreads();
    for (int off = 1; off < 256; off <<= 1) {
        int t = (threadIdx.x >= off) ? sm[threadIdx.x - off] : 0;
        __syncthreads();
        sm[threadIdx.x] += t;
        __syncthreads();
    }
    if (i < n) rowptr[i + 1] = sm[threadIdx.x];
    if (threadIdx.x == 255) bsum[blockIdx.x] = sm[255];
}

__global__ __launch_bounds__(256) void scan2_kernel(int* bsum, int nb) {
    __shared__ int sm[256];
    int v = (threadIdx.x < nb) ? bsum[threadIdx.x] : 0;
    sm[threadIdx.x] = v;
    __syncthreads();
    for (int off = 1; off < 256; off <<= 1) {
        int t = (threadIdx.x >= off) ? sm[threadIdx.x - off] : 0;
        __syncthreads();
        sm[threadIdx.x] += t;
        __syncthreads();
    }
    if (threadIdx.x < nb) bsum[threadIdx.x] = sm[threadIdx.x];
}

__global__ __launch_bounds__(256) void scan3_kernel(int* rowptr, const int* bsum, int n) {
    int i = blockIdx.x * 256 + threadIdx.x;
    if (i < n && blockIdx.x > 0) rowptr[i + 1] += bsum[blockIdx.x - 1];
    if (i == 0) rowptr[0] = 0;
}

__global__ void selffill_kernel(const int* rowptr, int* csr, int* fill, int N) {
    int n = blockIdx.x * 256 + threadIdx.x;
    if (n >= N) return;
    int rp = rowptr[n];
    csr[rp] = n;        // self-loop occupies slot 0 of each row
    fill[n] = rp + 1;
}

// dst-sliced scatter: csr writes confined to an L2-resident window per pass
__global__ void scatter_kernel(const int* __restrict__ src32, const int* __restrict__ dst32,
                               int E, int lo, int hi, int* fill, int* csr) {
    int e = blockIdx.x * 256 + threadIdx.x;
    if (e >= E) return;
    int d = dst32[e];
    if (d < lo || d >= hi) return;
    int p = atomicAdd(&fill[d], 1);
    csr[p] = src32[e];
}

// ---------------- precompute u = (W2^T a2) * log2(e) per head ----------------
__global__ __launch_bounds__(64) void prep_u_kernel(
        const float* __restrict__ W2, const float* __restrict__ a2s,
        const float* __restrict__ a2d, float* __restrict__ u_s, float* __restrict__ u_d) {
    int l = threadIdx.x;  // 0..63
    int h = l >> 5, k = l & 31;
    float us = 0.f, ud = 0.f;
    for (int c = 0; c < 32; c++) {
        float w = W2[(h * 32 + c) * 32 + k];
        us += a2s[h * 32 + c] * w;
        ud += a2d[h * 32 + c] * w;
    }
    u_s[l] = us * LOG2E;   // exp2 trick: lrelu is positively homogeneous
    u_d[l] = ud * LOG2E;
}

// ---------------- pack W2 into half2 k-pairs (0.5 mean-heads factor folded in) ----------------
// w2h[kp*64 + r] = half2(0.5*W2[r][2kp], 0.5*W2[r][2kp+1]);  r = h*32 + c (row of W2)
__global__ __launch_bounds__(256) void pack_kernel(
        const float* __restrict__ W2, __half2* __restrict__ w2h) {
    int idx = blockIdx.x * 256 + threadIdx.x;
    if (idx >= 1024) return;
    int kp = idx >> 6, r = idx & 63;
    float a = 0.5f * W2[r * 32 + 2 * kp];
    float b = 0.5f * W2[r * 32 + 2 * kp + 1];
    w2h[idx] = __floats2half2_rn(a, b);
}

// ---------------- pack GRU weights into MFMA B-fragments (f16) ----------------
// v_mfma_f32_16x16x16f16 B layout: lane l holds B[k = 4*(l/16)+b][n = l%16], b=0..3.
__global__ __launch_bounds__(256) void packfrag_kernel(
        const float* __restrict__ w_ih, const float* __restrict__ w_hh,
        uint2* __restrict__ wfrag) {
    int idx = blockIdx.x * 256 + threadIdx.x;
    if (idx >= 1536) return;
    int q24 = idx >> 6, l = idx & 63;  // q24 0..23: 0-11 Wih, 12-23 Whh
    int c = l & 15, g = l >> 4;
    const float* W = (q24 < 12) ? w_ih : w_hh;
    int q = (q24 < 12) ? q24 : q24 - 12;
    int nt = q >> 1, kt = q & 1;
    float v[4];
#pragma unroll
    for (int b = 0; b < 4; b++) {
        int kk = kt * 16 + 4 * g + b;
        int nn = nt * 16 + c;
        v[b] = W[nn * 32 + kk];
    }
    __half2 lo = __floats2half2_rn(v[0], v[1]);
    __half2 hi = __floats2half2_rn(v[2], v[3]);
    uint2 u;
    u.x = *(unsigned*)&lo;
    u.y = *(unsigned*)&hi;
    wfrag[(8 + q24) * 64 + l] = u;
}

// ---------------- ALL timesteps layer-1 scores ----------------
__global__ __launch_bounds__(256) void score1_all(
        const float* __restrict__ x_seq, const float* __restrict__ W1,
        const float* __restrict__ a1s, const float* __restrict__ a1d,
        float4* __restrict__ nrec4, float2* __restrict__ sd1, int N) {
    int t = blockIdx.x;
    int node = blockIdx.y * 256 + threadIdx.x;
    if (node >= N) return;
    const float* xp = x_seq + ((size_t)t * N + node) * FIN;
    float x0 = xp[0], x1 = xp[1], x2 = xp[2];
    float ps0 = 0.f, ps1 = 0.f, pd0 = 0.f, pd1 = 0.f;
    for (int c = 0; c < 32; c++) {
        float h0 = W1[c * 3] * x0 + W1[c * 3 + 1] * x1 + W1[c * 3 + 2] * x2;
        float h1 = W1[96 + c * 3] * x0 + W1[97 + c * 3] * x1 + W1[98 + c * 3] * x2;
        ps0 += h0 * a1s[c]; pd0 += h0 * a1d[c];
        ps1 += h1 * a1s[32 + c]; pd1 += h1 * a1d[32 + c];
    }
    ps0 *= LOG2E; ps1 *= LOG2E; pd0 *= LOG2E; pd1 *= LOG2E;
    unsigned u = (unsigned)__half_as_ushort(__float2half_rn(ps0)) |
                 ((unsigned)__half_as_ushort(__float2half_rn(ps1)) << 16);
    float4 r;
    r.x = x0; r.y = x1; r.z = x2; r.w = __uint_as_float(u);
    nrec4[(size_t)t * N + node] = r;
    sd1[(size_t)t * N + node] = make_float2(pd0, pd1);
}

__device__ __forceinline__ void unpack_scores(float wslot, float& s0, float& s1) {
    unsigned u = __float_as_uint(wslot);
    s0 = __half2float(__ushort_as_half((unsigned short)(u & 0xffffu)));
    s1 = __half2float(__ushort_as_half((unsigned short)(u >> 16)));
}

// ---------------- ALL timesteps GAT1 aggregate: thread-per-(dst,t) ----------------
__global__ __launch_bounds__(64) void aggA_all(
        const int* __restrict__ rowptr, const int* __restrict__ csr,
        const float4* __restrict__ nrec4, const float2* __restrict__ sd1,
        const float* __restrict__ W1, const float* __restrict__ b1,
        const float* __restrict__ u_s, const float* __restrict__ u_d,
        __half2* __restrict__ g1h, float2* __restrict__ ssd2, float2* __restrict__ sd2, int N) {
    int t = blockIdx.x;
    int dst = blockIdx.y * 64 + threadIdx.x;
    if (dst >= N) return;
    const float4* nr = nrec4 + (size_t)t * N;
    int rs = rowptr[dst], re = rowptr[dst + 1];
    float2 sdv = sd1[(size_t)t * N + dst];
    float q0 = 0, qx0 = 0, qx1 = 0, qx2 = 0;
    float q1 = 0, qy0 = 0, qy1 = 0, qy2 = 0;
#define AGGA_EDGE(rr) { \
        float s0h, s1h; unpack_scores(rr.w, s0h, s1h); \
        float w0 = exp2f(lrelu(s0h + sdv.x)); \
        float w1 = exp2f(lrelu(s1h + sdv.y)); \
        q0 += w0; qx0 += w0 * rr.x; qx1 += w0 * rr.y; qx2 += w0 * rr.z; \
        q1 += w1; qy0 += w1 * rr.x; qy1 += w1 * rr.y; qy2 += w1 * rr.z; }
    int e = rs;
    for (; e + 4 <= re; e += 4) {
        int s0 = csr[e], s1 = csr[e + 1], s2 = csr[e + 2], s3 = csr[e + 3];
        float4 r0 = nr[s0], r1 = nr[s1], r2 = nr[s2], r3 = nr[s3];
        AGGA_EDGE(r0); AGGA_EDGE(r1); AGGA_EDGE(r2); AGGA_EDGE(r3);
    }
    for (; e < re; e++) {
        float4 r = nr[csr[e]];
        AGGA_EDGE(r);
    }
#undef AGGA_EDGE
    float inv0 = 1.f / (q0 + 1e-16f), inv1 = 1.f / (q1 + 1e-16f);
    float ax0 = qx0 * inv0, ax1 = qx1 * inv0, ax2 = qx2 * inv0;
    float ay0 = qy0 * inv1, ay1 = qy1 * inv1, ay2 = qy2 * inv1;
    float ps0 = 0, ps1 = 0, pd0 = 0, pd1 = 0;
    float4 out[4];
    __half2* ghp = (__half2*)out;
    float gprev = 0.f;
#pragma unroll
    for (int c = 0; c < 32; c++) {
        float v0 = W1[c * 3] * ax0 + W1[c * 3 + 1] * ax1 + W1[c * 3 + 2] * ax2;
        float v1 = W1[96 + c * 3] * ay0 + W1[97 + c * 3] * ay1 + W1[98 + c * 3] * ay2;
        float g = fmaxf(0.5f * (v0 + v1) + b1[c], 0.f);  // mean heads + bias + relu
        ps0 += g * u_s[c];      ps1 += g * u_s[32 + c];   // u_* already log2e-scaled
        pd0 += g * u_d[c];      pd1 += g * u_d[32 + c];
        if (c & 1) ghp[c >> 1] = __floats2half2_rn(gprev, g);
        else gprev = g;
    }
    float4* gdst = (float4*)(g1h + (size_t)t * N * 16 + (size_t)dst * 16);
    gdst[0] = out[0]; gdst[1] = out[1]; gdst[2] = out[2]; gdst[3] = out[3];
    ssd2[(size_t)t * N + dst] = make_float2(ps0, ps1);
    sd2[(size_t)t * N + dst]  = make_float2(pd0, pd1);
}

// ---------------- ALL t: GAT2 aggregate, PAIR-per-dst (channel-split) + W2 epilogue ----------------
// 2 threads/dst: thread q owns channels q*16..q*16+15 (both heads). Each edge: pair's
// two 32B loads cover the full 64B g1 line in one instruction pair; scores computed 2x
// (vs 4x in quad); 16 v_pk_fma_f16/edge/thread with fp32 flush every <=16 edges.
// Epilogue: pair exchanges halves via shfl_xor(1) (no LDS/barrier), then dot2 W2 matvec.
__global__ __launch_bounds__(256) void aggBg2_all(
        const int* __restrict__ rowptr, const int* __restrict__ csr,
        const __half2* __restrict__ g1h,
        const float2* __restrict__ ssd2, const float2* __restrict__ sd2,
        const __half2* __restrict__ w2h, const float* __restrict__ b2,
        __half2* __restrict__ g2H, int N) {
    int t = blockIdx.x;
    int tid = threadIdx.x;
    int dst = blockIdx.y * 128 + (tid >> 1);
    int q = tid & 1;     // channel-half: q*16..q*16+15
    if (dst >= N) return;
    const __half2* gt = g1h + (size_t)t * N * 16 + q * 8;  // my 8 half2 of each row
    const float2* ss = ssd2 + (size_t)t * N;
    int rs = rowptr[dst], re = rowptr[dst + 1];
    float2 sdv = sd2[(size_t)t * N + dst];
    float den0 = 0.f, den1 = 0.f;
    float a0f[16], a1f[16];
#pragma unroll
    for (int j = 0; j < 16; j++) { a0f[j] = 0.f; a1f[j] = 0.f; }
    union Half { float4 f[2]; __half2 h[8]; };
#define AGGB_EDGE(sc, rr) { \
        float w0 = exp2f(lrelu(sc.x + sdv.x)); \
        float w1 = exp2f(lrelu(sc.y + sdv.y)); \
        den0 += w0; den1 += w1; \
        __half2 w0h = __float2half2_rn(w0); \
        __half2 w1h = __float2half2_rn(w1); \
        _Pragma("unroll") \
        for (int j = 0; j < 8; j++) { \
            p0[j] = __hfma2(w0h, rr.h[j], p0[j]); \
            p1[j] = __hfma2(w1h, rr.h[j], p1[j]); \
        } }
    int e = rs;
    while (e < re) {
        int lim = min(re, e + 16);  // fp16 partials over <=16 edges, then fp32 flush
        __half2 p0[8], p1[8];
        __half2 z = __floats2half2_rn(0.f, 0.f);
#pragma unroll
        for (int j = 0; j < 8; j++) { p0[j] = z; p1[j] = z; }
        for (; e + 2 <= lim; e += 2) {
            int s0 = csr[e], s1 = csr[e + 1];
            float2 c0 = ss[s0], c1 = ss[s1];
            const float4* r0p = (const float4*)(gt + (size_t)s0 * 16);
            const float4* r1p = (const float4*)(gt + (size_t)s1 * 16);
            Half r0, r1;
            r0.f[0] = r0p[0]; r0.f[1] = r0p[1];
            r1.f[0] = r1p[0]; r1.f[1] = r1p[1];
            AGGB_EDGE(c0, r0);
            AGGB_EDGE(c1, r1);
        }
        for (; e < lim; e++) {
            int s = csr[e];
            float2 c = ss[s];
            const float4* rp = (const float4*)(gt + (size_t)s * 16);
            Half r;
            r.f[0] = rp[0]; r.f[1] = rp[1];
            AGGB_EDGE(c, r);
        }
#pragma unroll
        for (int j = 0; j < 8; j++) {
            float2 v0 = __half22float2(p0[j]);
            float2 v1 = __half22float2(p1[j]);
            a0f[2 * j] += v0.x; a0f[2 * j + 1] += v0.y;
            a1f[2 * j] += v1.x; a1f[2 * j + 1] += v1.y;
        }
    }
#undef AGGB_EDGE
    // normalize my half into half2 pairs
    float i0 = 1.f / (den0 + 1e-16f), i1 = 1.f / (den1 + 1e-16f);
    __half2 an0[8], an1[8];
#pragma unroll
    for (int j = 0; j < 8; j++) {
        an0[j] = __floats2half2_rn(a0f[2 * j] * i0, a0f[2 * j + 1] * i0);
        an1[j] = __floats2half2_rn(a1f[2 * j] * i1, a1f[2 * j + 1] * i1);
    }
    // pair exchange: assemble full 16-pair vectors per head (partner lane = lane^1)
    __half2 f0[16], f1[16];
#pragma unroll
    for (int j = 0; j < 8; j++) {
        unsigned o0 = __shfl_xor(*(unsigned*)&an0[j], 1, 64);
        unsigned o1 = __shfl_xor(*(unsigned*)&an1[j], 1, 64);
        __half2 oh0 = *(__half2*)&o0;
        __half2 oh1 = *(__half2*)&o1;
        if (q == 0) {
            f0[j] = an0[j]; f0[8 + j] = oh0;
            f1[j] = an1[j]; f1[8 + j] = oh1;
        } else {
            f0[j] = oh0; f0[8 + j] = an0[j];
            f1[j] = oh1; f1[8 + j] = an1[j];
        }
    }
    // W2 epilogue: my 16 output channels (pairs cpg = q*8 .. q*8+7)
    __half2 og[8];
#pragma unroll
    for (int cp8 = 0; cp8 < 8; cp8++) {
        int cpg = q * 8 + cp8;
        float accA = 0.f, accB = 0.f;
#pragma unroll
        for (int kp = 0; kp < 16; kp++) {
            accA = fdot2h(f0[kp], w2h[kp * 64 + 2 * cpg], accA);
            accA = fdot2h(f1[kp], w2h[kp * 64 + 32 + 2 * cpg], accA);
            accB = fdot2h(f0[kp], w2h[kp * 64 + 2 * cpg + 1], accB);
            accB = fdot2h(f1[kp], w2h[kp * 64 + 32 + 2 * cpg + 1], accB);
        }
        float ga = fmaxf(accA + b2[2 * cpg], 0.f);
        float gb = fmaxf(accB + b2[2 * cpg + 1], 0.f);
        og[cp8] = __floats2half2_rn(ga, gb);
    }
    // write my 32B of the g2 row (pair covers the 64B row coalesced)
    float4* o = (float4*)(g2H + ((size_t)t * N + dst) * 16 + q * 8);
    o[0] = ((float4*)og)[0];
    o[1] = ((float4*)og)[1];
}

// ---------------- MFMA GRU: 1 wave / 16 nodes; gate weights in B-fragment VGPRs ----------------
__global__ __launch_bounds__(64) void gru_mfma(
        const __half2* __restrict__ g2H, const uint2* __restrict__ wfrag,
        const float* __restrict__ b_ih, const float* __restrict__ b_hh,
        const float* __restrict__ fc_w, const float* __restrict__ fc_b,
        float* __restrict__ out, int N) {
    __shared__ __align__(16) __half h_lds[16 * 36];
    int l = threadIdx.x;
    int c = l & 15;    // tile col / A row (node)
    int g4 = l >> 4;   // k/m block 0..3
    int node0 = blockIdx.x * 16;
    union FU { uint2 u; v4h h; };
    v4h Bih[6][2], Bhh[6][2];
#pragma unroll
    for (int nt = 0; nt < 6; nt++)
#pragma unroll
        for (int kt = 0; kt < 2; kt++) {
            FU f; f.u = wfrag[(8 + nt * 2 + kt) * 64 + l]; Bih[nt][kt] = f.h;
            f.u = wfrag[(20 + nt * 2 + kt) * 64 + l]; Bhh[nt][kt] = f.h;
        }
    float bir0 = b_ih[c], bir1 = b_ih[c + 16];
    float biz0 = b_ih[32 + c], biz1 = b_ih[48 + c];
    float bin0 = b_ih[64 + c], bin1 = b_ih[80 + c];
    float bhr0 = b_hh[c], bhr1 = b_hh[c + 16];
    float bhz0 = b_hh[32 + c], bhz1 = b_hh[48 + c];
    float bhn0 = b_hh[64 + c], bhn1 = b_hh[80 + c];
    float fcw0 = fc_w[c], fcw1 = fc_w[c + 16];
    v4f hold0 = {0.f, 0.f, 0.f, 0.f};
    v4f hold1 = {0.f, 0.f, 0.f, 0.f};
    const __half2* rowb = g2H + (size_t)(node0 + c) * 16;  // A row = node c
    for (int t = 0; t < T_STEPS; t++) {
        const __half2* rb = rowb + (size_t)t * N * 16;
        v4f Di[6], Dh[6];
#pragma unroll
        for (int nt = 0; nt < 6; nt++) { Di[nt] = {0.f, 0.f, 0.f, 0.f}; Dh[nt] = {0.f, 0.f, 0.f, 0.f}; }
#pragma unroll
        for (int kt = 0; kt < 2; kt++) {
            FU Ag; Ag.u = *(const uint2*)(rb + 2 * g4 + 8 * kt);
#pragma unroll
            for (int nt = 0; nt < 6; nt++)
                Di[nt] = __builtin_amdgcn_mfma_f32_16x16x16f16(Ag.h, Bih[nt][kt], Di[nt], 0, 0, 0);
        }
        if (t > 0) {
#pragma unroll
            for (int kt = 0; kt < 2; kt++) {
                FU Ah; Ah.u = *(const uint2*)&h_lds[c * 36 + 4 * g4 + 16 * kt];
#pragma unroll
                for (int nt = 0; nt < 6; nt++)
                    Dh[nt] = __builtin_amdgcn_mfma_f32_16x16x16f16(Ah.h, Bhh[nt][kt], Dh[nt], 0, 0, 0);
            }
        }
        v4f hn0, hn1;
#pragma unroll
        for (int i = 0; i < 4; i++) {
            {
                float rr = sigmoidf((Di[0][i] + bir0) + (Dh[0][i] + bhr0));
                float zz = sigmoidf((Di[2][i] + biz0) + (Dh[2][i] + bhz0));
                float cand = tanhf((Di[4][i] + bin0) + rr * (Dh[4][i] + bhn0));
                hn0[i] = (1.f - zz) * cand + zz * hold0[i];
            }
            {
                float rr = sigmoidf((Di[1][i] + bir1) + (Dh[1][i] + bhr1));
                float zz = sigmoidf((Di[3][i] + biz1) + (Dh[3][i] + bhz1));
                float cand = tanhf((Di[5][i] + bin1) + rr * (Dh[5][i] + bhn1));
                hn1[i] = (1.f - zz) * cand + zz * hold1[i];
            }
        }
        hold0 = hn0; hold1 = hn1;
        if (t < T_STEPS - 1) {
            __syncthreads();
#pragma unroll
            for (int i = 0; i < 4; i++) {
                int nrow = 4 * g4 + i;
                h_lds[nrow * 36 + c]      = __float2half_rn(hn0[i]);
                h_lds[nrow * 36 + c + 16] = __float2half_rn(hn1[i]);
            }
            __syncthreads();
        }
    }
#pragma unroll
    for (int i = 0; i < 4; i++) {
        float p = fcw0 * hold0[i] + fcw1 * hold1[i];
        p += __shfl_xor(p, 1, 64);
        p += __shfl_xor(p, 2, 64);
        p += __shfl_xor(p, 4, 64);
        p += __shfl_xor(p, 8, 64);
        if (c == 0) out[node0 + 4 * g4 + i] = p + fc_b[0];
    }
}

extern "C" void kernel_launch(void* const* d_in, const int* in_sizes, int n_in,
                              void* d_out, int out_size, void* d_ws, size_t ws_size,
                              hipStream_t stream) {
    const float* x_seq = (const float*)d_in[0];
    const float* W1  = (const float*)d_in[1];
    const float* a1s = (const float*)d_in[2];
    const float* a1d = (const float*)d_in[3];
    const float* b1  = (const float*)d_in[4];
    const float* W2  = (const float*)d_in[5];
    const float* a2s = (const float*)d_in[6];
    const float* a2d = (const float*)d_in[7];
    const float* b2  = (const float*)d_in[8];
    const float* w_ih = (const float*)d_in[9];
    const float* w_hh = (const float*)d_in[10];
    const float* b_ih = (const float*)d_in[11];
    const float* b_hh = (const float*)d_in[12];
    const float* fc_w = (const float*)d_in[13];
    const float* fc_b = (const float*)d_in[14];
    const void*  ei   = d_in[15];

    const int N = in_sizes[0] / (T_STEPS * FIN);  // 50000
    const int E = in_sizes[15] / 2;               // 800000
    const int NE = E + N;
    const int NB = (N + 255) / 256;               // per-256 blocks (196)
    const int NB64 = (N + 63) / 64;               // 64-node blocks (782)
    const int NB128 = (N + 127) / 128;            // 128-dst pair blocks (391)
    const int NB16 = (N + 15) / 16;               // 16-node blocks (3125)
    const int EB = (E + 255) / 256;

    char* ws = (char*)d_ws;
    size_t off = 0;
    auto alloc = [&](size_t bytes) -> void* {
        void* p = ws + off;
        off += (bytes + 255) & ~(size_t)255;
        return p;
    };
    int*     flag   = (int*)alloc(4);
    int*     rowptr = (int*)alloc((size_t)(N + 1) * 4);
    int*     cnt    = (int*)alloc((size_t)N * 4);        // reused as fill cursor
    int*     bsum   = (int*)alloc(256 * 4);
    int*     csr    = (int*)alloc((size_t)NE * 4);
    int*     src32  = (int*)alloc((size_t)E * 4);
    int*     dst32  = (int*)alloc((size_t)E * 4);
    float4*  nrec4  = (float4*)alloc((size_t)T_STEPS * N * 16);       // 6.4MB
    float2*  sd1    = (float2*)alloc((size_t)T_STEPS * N * 8);        // 3.2MB
    float2*  ssd2   = (float2*)alloc((size_t)T_STEPS * N * 8);        // 3.2MB
    float2*  sd2    = (float2*)alloc((size_t)T_STEPS * N * 8);        // 3.2MB
    __half2* g1h    = (__half2*)alloc((size_t)T_STEPS * N * 16 * 4);  // 25.6MB
    __half2* g2H    = (__half2*)alloc((size_t)T_STEPS * N * 16 * 4);  // 25.6MB (fp16 g2)
    float*   u_s    = (float*)alloc(64 * 4);
    float*   u_d    = (float*)alloc(64 * 4);
    __half2* w2h    = (__half2*)alloc(1024 * 4);                      // half2-packed 0.5*W2
    uint2*   wfrag  = (uint2*)alloc(32 * 64 * 8);                     // B-fragments
    if (off > ws_size) return;  // workspace too small — cannot proceed safely

    // ---- preprocessing: CSR by destination (reused for all 16 aggregations) ----
    detect_kernel<<<1, 128, 0, stream>>>((const int*)ei, in_sizes[15], flag);
    init_kernel<<<NB, 256, 0, stream>>>(cnt, N);
    conv_count_kernel<<<EB, 256, 0, stream>>>(ei, flag, E, N, src32, dst32, cnt);
    scan1_kernel<<<NB, 256, 0, stream>>>(cnt, rowptr, bsum, N);
    scan2_kernel<<<1, 256, 0, stream>>>(bsum, NB);
    scan3_kernel<<<NB, 256, 0, stream>>>(rowptr, bsum, N);
    selffill_kernel<<<NB, 256, 0, stream>>>(rowptr, csr, cnt, N);
    {
        const int NPASS = 2;
        int per = (N + NPASS - 1) / NPASS;
        for (int p = 0; p < NPASS; p++) {
            int lo = p * per;
            int hi = min(lo + per, N);
            scatter_kernel<<<EB, 256, 0, stream>>>(src32, dst32, E, lo, hi, cnt, csr);
        }
    }
    prep_u_kernel<<<1, 64, 0, stream>>>(W2, a2s, a2d, u_s, u_d);
    pack_kernel<<<4, 256, 0, stream>>>(W2, w2h);
    packfrag_kernel<<<6, 256, 0, stream>>>(w_ih, w_hh, wfrag);

    // ---- ALL timesteps batched (only the GRU recurrence is serial) ----
    score1_all<<<dim3(T_STEPS, NB), 256, 0, stream>>>(x_seq, W1, a1s, a1d, nrec4, sd1, N);
    aggA_all<<<dim3(T_STEPS, NB64), 64, 0, stream>>>(rowptr, csr, nrec4, sd1, W1, b1,
                                                     u_s, u_d, g1h, ssd2, sd2, N);
    aggBg2_all<<<dim3(T_STEPS, NB128), 256, 0, stream>>>(rowptr, csr, g1h, ssd2, sd2,
                                                         w2h, b2, g2H, N);
    gru_mfma<<<NB16, 64, 0, stream>>>(g2H, wfrag, b_ih, b_hh,
                                      fc_w, fc_b, (float*)d_out, N);
}

// Round 21
// 289.756 us; speedup vs baseline: 1.1213x; 1.1213x over previous
//
#include <hip/hip_runtime.h>
#include <hip/hip_fp16.h>
#include <stdint.h>

#define T_STEPS 8
#define FIN 3
#define HID 32
#define NEG_SLOPE 0.2f
#define LOG2E 1.4426950408889634f

typedef __fp16 v4h __attribute__((ext_vector_type(4)));
typedef __fp16 v2h __attribute__((ext_vector_type(2)));
typedef float  v4f __attribute__((ext_vector_type(4)));

__device__ __forceinline__ float lrelu(float x) { return x > 0.f ? x : NEG_SLOPE * x; }
__device__ __forceinline__ float sigmoidf(float x) { return 1.f / (1.f + __expf(-x)); }

__device__ __forceinline__ float fdot2h(__half2 a, __half2 b, float c) {
#if __has_builtin(__builtin_amdgcn_fdot2)
    union { __half2 h; v2h v; } ua, ub;
    ua.h = a; ub.h = b;
    return __builtin_amdgcn_fdot2(ua.v, ub.v, c, false);
#else
    float2 fa = __half22float2(a), fb = __half22float2(b);
    return c + fa.x * fb.x + fa.y * fb.y;
#endif
}

// ---------------- edge dtype detection (int64 vs int32) ----------------
__global__ void detect_kernel(const int* ei32, int nElems, int* flag) {
    __shared__ int any_nonzero;
    if (threadIdx.x == 0) any_nonzero = 0;
    __syncthreads();
    int idx = 1 + 2 * (int)threadIdx.x;  // odd int32 slots
    if (idx < nElems && ei32[idx] != 0) any_nonzero = 1;  // benign race
    __syncthreads();
    if (threadIdx.x == 0) *flag = (any_nonzero ? 0 : 1);  // 1 => int64
}

__device__ __forceinline__ int get_edge(const void* ei, int is64, long long idx) {
    if (is64) return (int)((const long long*)ei)[idx];
    return ((const int*)ei)[idx];
}

__global__ void init_kernel(int* cnt, int N) {
    int i = blockIdx.x * 256 + threadIdx.x;
    if (i < N) cnt[i] = 1;  // self-loop pre-counted
}

// fused: int32 conversion + validity clamp + per-dst count
__global__ void conv_count_kernel(const void* ei, const int* flag, int E, int N,
                                  int* src32, int* dst32, int* cnt) {
    int e = blockIdx.x * 256 + threadIdx.x;
    if (e >= E) return;
    int is64 = *flag;
    int s = get_edge(ei, is64, e);
    int d = get_edge(ei, is64, (long long)E + e);
    if ((unsigned)s >= (unsigned)N) s = 0;  // safety clamp
    src32[e] = s;
    int dd = ((unsigned)d < (unsigned)N) ? d : 0x7fffffff;  // sentinel: excluded everywhere
    dst32[e] = dd;
    if (dd < N) atomicAdd(&cnt[dd], 1);
}

// hierarchical scan
__global__ __launch_bounds__(256) void scan1_kernel(const int* cnt, int* rowptr, int* bsum, int n) {
    __shared__ int sm[256];
    int i = blockIdx.x * 256 + threadIdx.x;
    int v = (i < n) ? cnt[i] : 0;
    sm[threadIdx.x] = v;
    __syncthreads();
    for (int off = 1; off < 256; off <<= 1) {
        int t = (threadIdx.x >= off) ? sm[threadIdx.x - off] : 0;
        __syncthreads();
        sm[threadIdx.x] += t;
        __syncthreads();
    }
    if (i < n) rowptr[i + 1] = sm[threadIdx.x];
    if (threadIdx.x == 255) bsum[blockIdx.x] = sm[255];
}

__global__ __launch_bounds__(256) void scan2_kernel(int* bsum, int nb) {
    __shared__ int sm[256];
    int v = (threadIdx.x < nb) ? bsum[threadIdx.x] : 0;
    sm[threadIdx.x] = v;
    __syncthreads();
    for (int off = 1; off < 256; off <<= 1) {
        int t = (threadIdx.x >= off) ? sm[threadIdx.x - off] : 0;
        __syncthreads();
        sm[threadIdx.x] += t;
        __syncthreads();
    }
    if (threadIdx.x < nb) bsum[threadIdx.x] = sm[threadIdx.x];
}

__global__ __launch_bounds__(256) void scan3_kernel(int* rowptr, const int* bsum, int n) {
    int i = blockIdx.x * 256 + threadIdx.x;
    if (i < n && blockIdx.x > 0) rowptr[i + 1] += bsum[blockIdx.x - 1];
    if (i == 0) rowptr[0] = 0;
}

__global__ void selffill_kernel(const int* rowptr, int* csr, int* fill, int N) {
    int n = blockIdx.x * 256 + threadIdx.x;
    if (n >= N) return;
    int rp = rowptr[n];
    csr[rp] = n;        // self-loop occupies slot 0 of each row
    fill[n] = rp + 1;
}

// dst-sliced scatter: csr writes confined to an L2-resident window per pass
__global__ void scatter_kernel(const int* __restrict__ src32, const int* __restrict__ dst32,
                               int E, int lo, int hi, int* fill, int* csr) {
    int e = blockIdx.x * 256 + threadIdx.x;
    if (e >= E) return;
    int d = dst32[e];
    if (d < lo || d >= hi) return;
    int p = atomicAdd(&fill[d], 1);
    csr[p] = src32[e];
}

// ---------------- precompute u = (W2^T a2) * log2(e) per head ----------------
__global__ __launch_bounds__(64) void prep_u_kernel(
        const float* __restrict__ W2, const float* __restrict__ a2s,
        const float* __restrict__ a2d, float* __restrict__ u_s, float* __restrict__ u_d) {
    int l = threadIdx.x;  // 0..63
    int h = l >> 5, k = l & 31;
    float us = 0.f, ud = 0.f;
    for (int c = 0; c < 32; c++) {
        float w = W2[(h * 32 + c) * 32 + k];
        us += a2s[h * 32 + c] * w;
        ud += a2d[h * 32 + c] * w;
    }
    u_s[l] = us * LOG2E;   // exp2 trick: lrelu is positively homogeneous
    u_d[l] = ud * LOG2E;
}

// ---------------- pack W2 into half2 k-pairs (0.5 mean-heads factor folded in) ----------------
// w2h[kp*64 + r] = half2(0.5*W2[r][2kp], 0.5*W2[r][2kp+1]);  r = h*32 + c (row of W2)
__global__ __launch_bounds__(256) void pack_kernel(
        const float* __restrict__ W2, __half2* __restrict__ w2h) {
    int idx = blockIdx.x * 256 + threadIdx.x;
    if (idx >= 1024) return;
    int kp = idx >> 6, r = idx & 63;
    float a = 0.5f * W2[r * 32 + 2 * kp];
    float b = 0.5f * W2[r * 32 + 2 * kp + 1];
    w2h[idx] = __floats2half2_rn(a, b);
}

// ---------------- pack GRU weights into MFMA B-fragments (f16) ----------------
// v_mfma_f32_16x16x16f16 B layout: lane l holds B[k = 4*(l/16)+b][n = l%16], b=0..3.
__global__ __launch_bounds__(256) void packfrag_kernel(
        const float* __restrict__ w_ih, const float* __restrict__ w_hh,
        uint2* __restrict__ wfrag) {
    int idx = blockIdx.x * 256 + threadIdx.x;
    if (idx >= 1536) return;
    int q24 = idx >> 6, l = idx & 63;  // q24 0..23: 0-11 Wih, 12-23 Whh
    int c = l & 15, g = l >> 4;
    const float* W = (q24 < 12) ? w_ih : w_hh;
    int q = (q24 < 12) ? q24 : q24 - 12;
    int nt = q >> 1, kt = q & 1;
    float v[4];
#pragma unroll
    for (int b = 0; b < 4; b++) {
        int kk = kt * 16 + 4 * g + b;
        int nn = nt * 16 + c;
        v[b] = W[nn * 32 + kk];
    }
    __half2 lo = __floats2half2_rn(v[0], v[1]);
    __half2 hi = __floats2half2_rn(v[2], v[3]);
    uint2 u;
    u.x = *(unsigned*)&lo;
    u.y = *(unsigned*)&hi;
    wfrag[(8 + q24) * 64 + l] = u;
}

// ---------------- ALL timesteps layer-1 scores ----------------
__global__ __launch_bounds__(256) void score1_all(
        const float* __restrict__ x_seq, const float* __restrict__ W1,
        const float* __restrict__ a1s, const float* __restrict__ a1d,
        float4* __restrict__ nrec4, float2* __restrict__ sd1, int N) {
    int t = blockIdx.x;
    int node = blockIdx.y * 256 + threadIdx.x;
    if (node >= N) return;
    const float* xp = x_seq + ((size_t)t * N + node) * FIN;
    float x0 = xp[0], x1 = xp[1], x2 = xp[2];
    float ps0 = 0.f, ps1 = 0.f, pd0 = 0.f, pd1 = 0.f;
    for (int c = 0; c < 32; c++) {
        float h0 = W1[c * 3] * x0 + W1[c * 3 + 1] * x1 + W1[c * 3 + 2] * x2;
        float h1 = W1[96 + c * 3] * x0 + W1[97 + c * 3] * x1 + W1[98 + c * 3] * x2;
        ps0 += h0 * a1s[c]; pd0 += h0 * a1d[c];
        ps1 += h1 * a1s[32 + c]; pd1 += h1 * a1d[32 + c];
    }
    ps0 *= LOG2E; ps1 *= LOG2E; pd0 *= LOG2E; pd1 *= LOG2E;
    unsigned u = (unsigned)__half_as_ushort(__float2half_rn(ps0)) |
                 ((unsigned)__half_as_ushort(__float2half_rn(ps1)) << 16);
    float4 r;
    r.x = x0; r.y = x1; r.z = x2; r.w = __uint_as_float(u);
    nrec4[(size_t)t * N + node] = r;
    sd1[(size_t)t * N + node] = make_float2(pd0, pd1);
}

__device__ __forceinline__ void unpack_scores(float wslot, float& s0, float& s1) {
    unsigned u = __float_as_uint(wslot);
    s0 = __half2float(__ushort_as_half((unsigned short)(u & 0xffffu)));
    s1 = __half2float(__ushort_as_half((unsigned short)(u >> 16)));
}

// ---------------- ALL timesteps GAT1 aggregate: thread-per-(dst,t) ----------------
__global__ __launch_bounds__(64) void aggA_all(
        const int* __restrict__ rowptr, const int* __restrict__ csr,
        const float4* __restrict__ nrec4, const float2* __restrict__ sd1,
        const float* __restrict__ W1, const float* __restrict__ b1,
        const float* __restrict__ u_s, const float* __restrict__ u_d,
        __half2* __restrict__ g1h, float2* __restrict__ ssd2, float2* __restrict__ sd2, int N) {
    int t = blockIdx.x;
    int dst = blockIdx.y * 64 + threadIdx.x;
    if (dst >= N) return;
    const float4* nr = nrec4 + (size_t)t * N;
    int rs = rowptr[dst], re = rowptr[dst + 1];
    float2 sdv = sd1[(size_t)t * N + dst];
    float q0 = 0, qx0 = 0, qx1 = 0, qx2 = 0;
    float q1 = 0, qy0 = 0, qy1 = 0, qy2 = 0;
#define AGGA_EDGE(rr) { \
        float s0h, s1h; unpack_scores(rr.w, s0h, s1h); \
        float w0 = exp2f(lrelu(s0h + sdv.x)); \
        float w1 = exp2f(lrelu(s1h + sdv.y)); \
        q0 += w0; qx0 += w0 * rr.x; qx1 += w0 * rr.y; qx2 += w0 * rr.z; \
        q1 += w1; qy0 += w1 * rr.x; qy1 += w1 * rr.y; qy2 += w1 * rr.z; }
    int e = rs;
    for (; e + 4 <= re; e += 4) {
        int s0 = csr[e], s1 = csr[e + 1], s2 = csr[e + 2], s3 = csr[e + 3];
        float4 r0 = nr[s0], r1 = nr[s1], r2 = nr[s2], r3 = nr[s3];
        AGGA_EDGE(r0); AGGA_EDGE(r1); AGGA_EDGE(r2); AGGA_EDGE(r3);
    }
    for (; e < re; e++) {
        float4 r = nr[csr[e]];
        AGGA_EDGE(r);
    }
#undef AGGA_EDGE
    float inv0 = 1.f / (q0 + 1e-16f), inv1 = 1.f / (q1 + 1e-16f);
    float ax0 = qx0 * inv0, ax1 = qx1 * inv0, ax2 = qx2 * inv0;
    float ay0 = qy0 * inv1, ay1 = qy1 * inv1, ay2 = qy2 * inv1;
    float ps0 = 0, ps1 = 0, pd0 = 0, pd1 = 0;
    float4 out[4];
    __half2* ghp = (__half2*)out;
    float gprev = 0.f;
#pragma unroll
    for (int c = 0; c < 32; c++) {
        float v0 = W1[c * 3] * ax0 + W1[c * 3 + 1] * ax1 + W1[c * 3 + 2] * ax2;
        float v1 = W1[96 + c * 3] * ay0 + W1[97 + c * 3] * ay1 + W1[98 + c * 3] * ay2;
        float g = fmaxf(0.5f * (v0 + v1) + b1[c], 0.f);  // mean heads + bias + relu
        ps0 += g * u_s[c];      ps1 += g * u_s[32 + c];   // u_* already log2e-scaled
        pd0 += g * u_d[c];      pd1 += g * u_d[32 + c];
        if (c & 1) ghp[c >> 1] = __floats2half2_rn(gprev, g);
        else gprev = g;
    }
    float4* gdst = (float4*)(g1h + (size_t)t * N * 16 + (size_t)dst * 16);
    gdst[0] = out[0]; gdst[1] = out[1]; gdst[2] = out[2]; gdst[3] = out[3];
    ssd2[(size_t)t * N + dst] = make_float2(ps0, ps1);
    sd2[(size_t)t * N + dst]  = make_float2(pd0, pd1);
}

// ---------------- ALL t: GAT2 aggregate (quad, packed-f16 FMA) + W2 epilogue (dot2) ----------------
// Inner loop: 8 channels/head accumulated as 4 hfma2 (v_pk_fma_f16), flushed to fp32
// every <=16 edges (bounded fp16 error). Phase 2: W2 matvec via v_dot2_f32_f16
// with half2-packed K$-resident weights (0.5 folded). Output fp16 g2 (64B/node/t).
__global__ __launch_bounds__(256) void aggBg2_all(
        const int* __restrict__ rowptr, const int* __restrict__ csr,
        const __half2* __restrict__ g1h,
        const float2* __restrict__ ssd2, const float2* __restrict__ sd2,
        const __half2* __restrict__ w2h, const float* __restrict__ b2,
        __half2* __restrict__ g2H, int N) {
    __shared__ __half2 a_lds[64 * 33];  // [dl][pair]: 0-15 head0 agg, 16-31 head1 agg
    int t = blockIdx.x;
    int tid = threadIdx.x;
    int node0 = blockIdx.y * 64;
    int dl = tid >> 2;   // local dst 0..63
    int q = tid & 3;     // quarter: channels q*8..q*8+7 per head
    int dst = node0 + dl;
    if (dst < N) {
        const __half2* gbase = g1h + (size_t)t * N * 16 + q * 4;
        const float2* ss = ssd2 + (size_t)t * N;
        int rs = rowptr[dst], re = rowptr[dst + 1];
        float2 sdv = sd2[(size_t)t * N + dst];
        float a0[8] = {0, 0, 0, 0, 0, 0, 0, 0};
        float a1[8] = {0, 0, 0, 0, 0, 0, 0, 0};
        float den0 = 0.f, den1 = 0.f;
#define AGGB_EDGE(sc, gv) { \
        float w0 = exp2f(lrelu(sc.x + sdv.x)); \
        float w1 = exp2f(lrelu(sc.y + sdv.y)); \
        den0 += w0; den1 += w1; \
        __half2 w0h = __float2half2_rn(w0); \
        __half2 w1h = __float2half2_rn(w1); \
        const __half2* p = (const __half2*)&(gv); \
        h0[0] = __hfma2(w0h, p[0], h0[0]); h0[1] = __hfma2(w0h, p[1], h0[1]); \
        h0[2] = __hfma2(w0h, p[2], h0[2]); h0[3] = __hfma2(w0h, p[3], h0[3]); \
        h1[0] = __hfma2(w1h, p[0], h1[0]); h1[1] = __hfma2(w1h, p[1], h1[1]); \
        h1[2] = __hfma2(w1h, p[2], h1[2]); h1[3] = __hfma2(w1h, p[3], h1[3]); }
        int e = rs;
        while (e < re) {
            int lim = min(re, e + 16);  // fp16 partial over <=16 edges, then fp32 flush
            __half2 h0[4], h1[4];
#pragma unroll
            for (int j = 0; j < 4; j++) {
                h0[j] = __floats2half2_rn(0.f, 0.f);
                h1[j] = __floats2half2_rn(0.f, 0.f);
            }
            for (; e + 4 <= lim; e += 4) {
                int s0 = csr[e], s1 = csr[e + 1], s2 = csr[e + 2], s3 = csr[e + 3];
                float2 c0 = ss[s0], c1 = ss[s1], c2 = ss[s2], c3 = ss[s3];
                float4 g0 = *(const float4*)(gbase + (size_t)s0 * 16);
                float4 g1 = *(const float4*)(gbase + (size_t)s1 * 16);
                float4 g2 = *(const float4*)(gbase + (size_t)s2 * 16);
                float4 g3 = *(const float4*)(gbase + (size_t)s3 * 16);
                AGGB_EDGE(c0, g0); AGGB_EDGE(c1, g1); AGGB_EDGE(c2, g2); AGGB_EDGE(c3, g3);
            }
            for (; e < lim; e++) {
                int s = csr[e];
                float2 c = ss[s];
                float4 g = *(const float4*)(gbase + (size_t)s * 16);
                AGGB_EDGE(c, g);
            }
#pragma unroll
            for (int j = 0; j < 4; j++) {
                float2 v0 = __half22float2(h0[j]);
                float2 v1 = __half22float2(h1[j]);
                a0[2 * j] += v0.x; a0[2 * j + 1] += v0.y;
                a1[2 * j] += v1.x; a1[2 * j + 1] += v1.y;
            }
        }
#undef AGGB_EDGE
        float i0 = 1.f / (den0 + 1e-16f), i1 = 1.f / (den1 + 1e-16f);
#pragma unroll
        for (int j = 0; j < 4; j++) {
            a_lds[dl * 33 + q * 4 + j]      = __floats2half2_rn(a0[2 * j] * i0, a0[2 * j + 1] * i0);
            a_lds[dl * 33 + 16 + q * 4 + j] = __floats2half2_rn(a1[2 * j] * i1, a1[2 * j + 1] * i1);
        }
    }
    __syncthreads();
    // ---- phase 2: g2 = relu((0.5*W2)·agg + b2) via v_dot2_f32_f16, wave-uniform cg8 ----
    int nl = tid & 63;
    int cg8 = __builtin_amdgcn_readfirstlane((tid >> 6) * 8);
    int node = node0 + nl;
    if (node >= N) return;
    float acc[8] = {0, 0, 0, 0, 0, 0, 0, 0};
    for (int kp = 0; kp < 16; kp++) {
        __half2 A0 = a_lds[nl * 33 + kp];        // head0 agg ch pair (2kp, 2kp+1)
        __half2 A1 = a_lds[nl * 33 + 16 + kp];   // head1 agg ch pair
        const __half2* w0p = w2h + kp * 64 + cg8;       // head0 rows, channels cg8..+7
        const __half2* w1p = w2h + kp * 64 + 32 + cg8;  // head1 rows
#pragma unroll
        for (int j = 0; j < 8; j++) {
            acc[j] = fdot2h(A0, w0p[j], acc[j]);
            acc[j] = fdot2h(A1, w1p[j], acc[j]);
        }
    }
    __half2 o[4];
#pragma unroll
    for (int j = 0; j < 4; j++) {
        float ga = fmaxf(acc[2 * j] + b2[cg8 + 2 * j], 0.f);
        float gb = fmaxf(acc[2 * j + 1] + b2[cg8 + 2 * j + 1], 0.f);
        o[j] = __floats2half2_rn(ga, gb);
    }
    // g2 row = 16 half2 (32 ch); this thread writes 4 half2 = 16B (4 threads/node -> 64B)
    *(float4*)(g2H + ((size_t)t * N + node) * 16 + (cg8 >> 1)) = *(float4*)o;
}

// ---------------- MFMA GRU: 1 wave / 16 nodes; gate weights in B-fragment VGPRs ----------------
__global__ __launch_bounds__(64) void gru_mfma(
        const __half2* __restrict__ g2H, const uint2* __restrict__ wfrag,
        const float* __restrict__ b_ih, const float* __restrict__ b_hh,
        const float* __restrict__ fc_w, const float* __restrict__ fc_b,
        float* __restrict__ out, int N) {
    __shared__ __align__(16) __half h_lds[16 * 36];
    int l = threadIdx.x;
    int c = l & 15;    // tile col / A row (node)
    int g4 = l >> 4;   // k/m block 0..3
    int node0 = blockIdx.x * 16;
    union FU { uint2 u; v4h h; };
    v4h Bih[6][2], Bhh[6][2];
#pragma unroll
    for (int nt = 0; nt < 6; nt++)
#pragma unroll
        for (int kt = 0; kt < 2; kt++) {
            FU f; f.u = wfrag[(8 + nt * 2 + kt) * 64 + l]; Bih[nt][kt] = f.h;
            f.u = wfrag[(20 + nt * 2 + kt) * 64 + l]; Bhh[nt][kt] = f.h;
        }
    float bir0 = b_ih[c], bir1 = b_ih[c + 16];
    float biz0 = b_ih[32 + c], biz1 = b_ih[48 + c];
    float bin0 = b_ih[64 + c], bin1 = b_ih[80 + c];
    float bhr0 = b_hh[c], bhr1 = b_hh[c + 16];
    float bhz0 = b_hh[32 + c], bhz1 = b_hh[48 + c];
    float bhn0 = b_hh[64 + c], bhn1 = b_hh[80 + c];
    float fcw0 = fc_w[c], fcw1 = fc_w[c + 16];
    v4f hold0 = {0.f, 0.f, 0.f, 0.f};
    v4f hold1 = {0.f, 0.f, 0.f, 0.f};
    const __half2* rowb = g2H + (size_t)(node0 + c) * 16;  // A row = node c
    for (int t = 0; t < T_STEPS; t++) {
        const __half2* rb = rowb + (size_t)t * N * 16;
        v4f Di[6], Dh[6];
#pragma unroll
        for (int nt = 0; nt < 6; nt++) { Di[nt] = {0.f, 0.f, 0.f, 0.f}; Dh[nt] = {0.f, 0.f, 0.f, 0.f}; }
#pragma unroll
        for (int kt = 0; kt < 2; kt++) {
            FU Ag; Ag.u = *(const uint2*)(rb + 2 * g4 + 8 * kt);
#pragma unroll
            for (int nt = 0; nt < 6; nt++)
                Di[nt] = __builtin_amdgcn_mfma_f32_16x16x16f16(Ag.h, Bih[nt][kt], Di[nt], 0, 0, 0);
        }
        if (t > 0) {
#pragma unroll
            for (int kt = 0; kt < 2; kt++) {
                FU Ah; Ah.u = *(const uint2*)&h_lds[c * 36 + 4 * g4 + 16 * kt];
#pragma unroll
                for (int nt = 0; nt < 6; nt++)
                    Dh[nt] = __builtin_amdgcn_mfma_f32_16x16x16f16(Ah.h, Bhh[nt][kt], Dh[nt], 0, 0, 0);
            }
        }
        v4f hn0, hn1;
#pragma unroll
        for (int i = 0; i < 4; i++) {
            {
                float rr = sigmoidf((Di[0][i] + bir0) + (Dh[0][i] + bhr0));
                float zz = sigmoidf((Di[2][i] + biz0) + (Dh[2][i] + bhz0));
                float cand = tanhf((Di[4][i] + bin0) + rr * (Dh[4][i] + bhn0));
                hn0[i] = (1.f - zz) * cand + zz * hold0[i];
            }
            {
                float rr = sigmoidf((Di[1][i] + bir1) + (Dh[1][i] + bhr1));
                float zz = sigmoidf((Di[3][i] + biz1) + (Dh[3][i] + bhz1));
                float cand = tanhf((Di[5][i] + bin1) + rr * (Dh[5][i] + bhn1));
                hn1[i] = (1.f - zz) * cand + zz * hold1[i];
            }
        }
        hold0 = hn0; hold1 = hn1;
        if (t < T_STEPS - 1) {
            __syncthreads();
#pragma unroll
            for (int i = 0; i < 4; i++) {
                int nrow = 4 * g4 + i;
                h_lds[nrow * 36 + c]      = __float2half_rn(hn0[i]);
                h_lds[nrow * 36 + c + 16] = __float2half_rn(hn1[i]);
            }
            __syncthreads();
        }
    }
#pragma unroll
    for (int i = 0; i < 4; i++) {
        float p = fcw0 * hold0[i] + fcw1 * hold1[i];
        p += __shfl_xor(p, 1, 64);
        p += __shfl_xor(p, 2, 64);
        p += __shfl_xor(p, 4, 64);
        p += __shfl_xor(p, 8, 64);
        if (c == 0) out[node0 + 4 * g4 + i] = p + fc_b[0];
    }
}

extern "C" void kernel_launch(void* const* d_in, const int* in_sizes, int n_in,
                              void* d_out, int out_size, void* d_ws, size_t ws_size,
                              hipStream_t stream) {
    const float* x_seq = (const float*)d_in[0];
    const float* W1  = (const float*)d_in[1];
    const float* a1s = (const float*)d_in[2];
    const float* a1d = (const float*)d_in[3];
    const float* b1  = (const float*)d_in[4];
    const float* W2  = (const float*)d_in[5];
    const float* a2s = (const float*)d_in[6];
    const float* a2d = (const float*)d_in[7];
    const float* b2  = (const float*)d_in[8];
    const float* w_ih = (const float*)d_in[9];
    const float* w_hh = (const float*)d_in[10];
    const float* b_ih = (const float*)d_in[11];
    const float* b_hh = (const float*)d_in[12];
    const float* fc_w = (const float*)d_in[13];
    const float* fc_b = (const float*)d_in[14];
    const void*  ei   = d_in[15];

    const int N = in_sizes[0] / (T_STEPS * FIN);  // 50000
    const int E = in_sizes[15] / 2;               // 800000
    const int NE = E + N;
    const int NB = (N + 255) / 256;               // per-256 blocks (196)
    const int NB64 = (N + 63) / 64;               // 64-node blocks (782)
    const int NB16 = (N + 15) / 16;               // 16-node blocks (3125)
    const int EB = (E + 255) / 256;

    char* ws = (char*)d_ws;
    size_t off = 0;
    auto alloc = [&](size_t bytes) -> void* {
        void* p = ws + off;
        off += (bytes + 255) & ~(size_t)255;
        return p;
    };
    int*     flag   = (int*)alloc(4);
    int*     rowptr = (int*)alloc((size_t)(N + 1) * 4);
    int*     cnt    = (int*)alloc((size_t)N * 4);        // reused as fill cursor
    int*     bsum   = (int*)alloc(256 * 4);
    int*     csr    = (int*)alloc((size_t)NE * 4);
    int*     src32  = (int*)alloc((size_t)E * 4);
    int*     dst32  = (int*)alloc((size_t)E * 4);
    float4*  nrec4  = (float4*)alloc((size_t)T_STEPS * N * 16);       // 6.4MB
    float2*  sd1    = (float2*)alloc((size_t)T_STEPS * N * 8);        // 3.2MB
    float2*  ssd2   = (float2*)alloc((size_t)T_STEPS * N * 8);        // 3.2MB
    float2*  sd2    = (float2*)alloc((size_t)T_STEPS * N * 8);        // 3.2MB
    __half2* g1h    = (__half2*)alloc((size_t)T_STEPS * N * 16 * 4);  // 25.6MB
    __half2* g2H    = (__half2*)alloc((size_t)T_STEPS * N * 16 * 4);  // 25.6MB (fp16 g2)
    float*   u_s    = (float*)alloc(64 * 4);
    float*   u_d    = (float*)alloc(64 * 4);
    __half2* w2h    = (__half2*)alloc(1024 * 4);                      // half2-packed 0.5*W2
    uint2*   wfrag  = (uint2*)alloc(32 * 64 * 8);                     // B-fragments
    if (off > ws_size) return;  // workspace too small — cannot proceed safely

    // ---- preprocessing: CSR by destination (reused for all 16 aggregations) ----
    detect_kernel<<<1, 128, 0, stream>>>((const int*)ei, in_sizes[15], flag);
    init_kernel<<<NB, 256, 0, stream>>>(cnt, N);
    conv_count_kernel<<<EB, 256, 0, stream>>>(ei, flag, E, N, src32, dst32, cnt);
    scan1_kernel<<<NB, 256, 0, stream>>>(cnt, rowptr, bsum, N);
    scan2_kernel<<<1, 256, 0, stream>>>(bsum, NB);
    scan3_kernel<<<NB, 256, 0, stream>>>(rowptr, bsum, N);
    selffill_kernel<<<NB, 256, 0, stream>>>(rowptr, csr, cnt, N);
    {
        const int NPASS = 2;
        int per = (N + NPASS - 1) / NPASS;
        for (int p = 0; p < NPASS; p++) {
            int lo = p * per;
            int hi = min(lo + per, N);
            scatter_kernel<<<EB, 256, 0, stream>>>(src32, dst32, E, lo, hi, cnt, csr);
        }
    }
    prep_u_kernel<<<1, 64, 0, stream>>>(W2, a2s, a2d, u_s, u_d);
    pack_kernel<<<4, 256, 0, stream>>>(W2, w2h);
    packfrag_kernel<<<6, 256, 0, stream>>>(w_ih, w_hh, wfrag);

    // ---- ALL timesteps batched (only the GRU recurrence is serial) ----
    score1_all<<<dim3(T_STEPS, NB), 256, 0, stream>>>(x_seq, W1, a1s, a1d, nrec4, sd1, N);
    aggA_all<<<dim3(T_STEPS, NB64), 64, 0, stream>>>(rowptr, csr, nrec4, sd1, W1, b1,
                                                     u_s, u_d, g1h, ssd2, sd2, N);
    aggBg2_all<<<dim3(T_STEPS, NB64), 256, 0, stream>>>(rowptr, csr, g1h, ssd2, sd2,
                                                        w2h, b2, g2H, N);
    gru_mfma<<<NB16, 64, 0, stream>>>(g2H, wfrag, b_ih, b_hh,
                                      fc_w, fc_b, (float*)d_out, N);
}